// Round 8
// baseline (105.132 us; speedup 1.0000x reference)
//
#include <hip/hip_runtime.h>
#include <stdint.h>

#define T_STEPS 2048
#define NCHUNK  86            // 85 full 24-step chunks + one 8-step tail chunk
#define LARGEF  1.0e9f
typedef unsigned long long u64;
typedef unsigned uint2v __attribute__((ext_vector_type(2)));

__device__ __forceinline__ int par6(int x) { return __builtin_popcount((unsigned)x) & 1; }

// dual-basis functionals C; exchange masks m={1,2,7,15,16,32} (verified r2-r7)
constexpr int CARR[6] = {5, 6, 12, 8, 16, 32};
constexpr int MARR[6] = {1, 2, 7, 15, 16, 32};

template<int CTRL>
__device__ __forceinline__ float xdpp(float x) {
  return __int_as_float(__builtin_amdgcn_update_dpp(0, __float_as_int(x), CTRL, 0xF, 0xF, true));
}
template<int CTRL>
__device__ __forceinline__ unsigned xdpp_u(unsigned x) {
  return (unsigned)__builtin_amdgcn_update_dpp(0, (int)x, CTRL, 0xF, 0xF, true);
}

// select by uniform 64-bit wave mask (SGPR pair): bit=1 -> take b_true
__device__ __forceinline__ unsigned selmask_u(unsigned a_false, unsigned b_true, u64 m) {
  unsigned out;
  asm("v_cndmask_b32 %0, %1, %2, %3" : "=v"(out) : "v"(a_false), "v"(b_true), "s"(m));
  return out;
}

__device__ __forceinline__ unsigned exch16_u(unsigned x, u64 mrx) {
#if __has_builtin(__builtin_amdgcn_permlane16_swap)
  uint2v r = __builtin_amdgcn_permlane16_swap(x, x, false, false);
  return selmask_u(r.y, r.x, mrx);
#else
  (void)mrx;
  return (unsigned)__builtin_amdgcn_ds_swizzle((int)x, 0x401F);
#endif
}
__device__ __forceinline__ unsigned exch32_u(unsigned x, u64 mrx) {
#if __has_builtin(__builtin_amdgcn_permlane32_swap)
  uint2v r = __builtin_amdgcn_permlane32_swap(x, x, false, false);
  return selmask_u(r.y, r.x, mrx);
#else
  (void)mrx;
  return (unsigned)__shfl_xor((int)x, 32, 64);
#endif
}
__device__ __forceinline__ float exch16_f(float x, u64 mrx) {
  return __uint_as_float(exch16_u(__float_as_uint(x), mrx));
}
__device__ __forceinline__ float exch32_f(float x, u64 mrx) {
  return __uint_as_float(exch32_u(__float_as_uint(x), mrx));
}

struct Ctx {
  // per round-phase RP=0,1,2 (phase pair 2RP, 2RP+1)
  float saeA[3], sbeA[3];     // phase-A signs at lane
  float saeA2[3], sbeA2[3];   // phase-A signs at lane^mB
  float saeB[3], sbeB[3];     // phase-B signs at lane
  unsigned pq0[3], pq1[3];    // pdA|pdB<<1 and pdA2|pdB<<1 (per-lane 0..3)
  u64 pdmA[3], pdmA2[3], pdmB[3];  // uniform parity masks for tie rules
  u64 mrx16, mrx32;           // permlane swap r.x-select masks
};

__device__ __forceinline__ void mk(int ph, int l, float& sae, float& sbe, int& pd) {
  const int pdv = par6(l & CARR[ph]);
  int t = 0;
#pragma unroll
  for (int j = 0; j < 5; ++j) t |= par6(l & CARR[(ph + 1 + j) % 6]) << j;
  t |= pdv << 5;
  const float sa = 1.0f - 2.0f * (float)par6(t & 45);   // poly 1011011
  const float sb = 1.0f - 2.0f * (float)par6(t & 60);   // poly 1111001
  sae = pdv ? -sa : sa;
  sbe = pdv ? -sb : sb;
  pd = pdv;
}

// ---- hoisted branch metrics: NR rounds (2 steps each) ----
template<int NR>
__device__ __forceinline__ void bmcalc3(const float4 (&fy)[12], float (&bmA)[12],
                                        float (&bmA2)[12], float (&bmB)[12], const Ctx& cx) {
#pragma unroll
  for (int r = 0; r < NR; ++r) {
    const int rp = r % 3;
    bmA[r]  = fmaf(cx.saeA[rp],  fy[r].x, cx.sbeA[rp]  * fy[r].y);   // bit-exact vs ref
    bmA2[r] = fmaf(cx.saeA2[rp], fy[r].x, cx.sbeA2[rp] * fy[r].y);
    bmB[r]  = fmaf(cx.saeB[rp],  fy[r].z, cx.sbeB[rp]  * fy[r].w);
  }
}

// ---- radix-4 rounds: round R covers steps 2R,2R+1; appends word bits 6+2R,7+2R ----
template<int NR, int R>
__device__ __forceinline__ void frounds(float& cum, unsigned& word,
                                        const float (&bmA)[12], const float (&bmA2)[12],
                                        const float (&bmB)[12], const Ctx& cx) {
  if constexpr (R < NR) {
    constexpr int RP = R % 3;
    float exA, exB_, exAB; unsigned wxA, wxB, wxAB;
    if constexpr (RP == 0) {            // masks 1,2,3 (quad_perm DPP)
      exA  = xdpp<0xB1>(cum);  exB_ = xdpp<0x4E>(cum);  exAB = xdpp<0x1B>(cum);
      wxA  = xdpp_u<0xB1>(word); wxB = xdpp_u<0x4E>(word); wxAB = xdpp_u<0x1B>(word);
    } else if constexpr (RP == 1) {     // masks 7,15,8 (row_half_mirror, row_mirror, row_ror:8)
      exA  = xdpp<0x141>(cum); exB_ = xdpp<0x140>(cum); exAB = xdpp<0x128>(cum);
      wxA  = xdpp_u<0x141>(word); wxB = xdpp_u<0x140>(word); wxAB = xdpp_u<0x128>(word);
    } else {                            // masks 16,32,48 (permlane swaps; 48 composed)
      exA  = exch16_f(cum, cx.mrx16);  exB_ = exch32_f(cum, cx.mrx32);
      exAB = exch16_f(exB_, cx.mrx16);
      wxA  = exch16_u(word, cx.mrx16); wxB  = exch32_u(word, cx.mrx32);
      wxAB = exch16_u(wxB, cx.mrx16);
    }
    // pre-B-add candidates (exact sequential intermediates cumA at l and l^mB)
    const float c00p = cum  + bmA[R];    // own path, own A-pred
    const float c01p = exA  - bmA[R];    // own path, partner A-pred
    const float c10p = exB_ + bmA2[R];   // partner intermediate, own A-pred
    const float c11p = exAB - bmA2[R];   // partner intermediate, partner A-pred
    const float u = fminf(c00p, c01p);   // = cumA(l)
    const float v = fminf(c10p, c11p);   // = cumA(l^mB)
    const float x  = u + bmB[R];
    const float yv = v - bmB[R];
    cum = fminf(x, yv);
    // survivor decisions: exact nested sequential tie rules
    const u64 a1 = __ballot(c01p < c00p), a2 = __ballot(c00p < c01p);
    const u64 o1 = __ballot(c11p < c10p), o2 = __ballot(c10p < c11p);
    const u64 f1 = __ballot(yv < x),      f2 = __ballot(x < yv);
    const u64 dA  = (a1 & ~cx.pdmA[RP])  | (cx.pdmA[RP]  & ~a2);
    const u64 dAo = (o1 & ~cx.pdmA2[RP]) | (cx.pdmA2[RP] & ~o2);
    const u64 dB  = (f1 & ~cx.pdmB[RP])  | (cx.pdmB[RP]  & ~f2);
    // word path: select ancestor + append the two decoded bits
    const unsigned wu = selmask_u(word, wxA, dA)  | (cx.pq0[RP] << (6 + 2 * R));
    const unsigned wv = selmask_u(wxB, wxAB, dAo) | (cx.pq1[RP] << (6 + 2 * R));
    word = selmask_u(wu, wv, dB);
    frounds<NR, R + 1>(cum, word, bmA, bmA2, bmB, cx);
  }
}

__global__ __launch_bounds__(64, 1) void viterbi_kernel(const float* __restrict__ in,
                                                        float* __restrict__ out) {
  __shared__ float y_lds[2 * T_STEPS];     // 16 KB staged input row
  __shared__ unsigned tbf[NCHUNK * 64];    // 21.5 KB flushed path/anc words

  const int b = blockIdx.x;
  const int lane = threadIdx.x;
  const float* yrow = in + (size_t)b * (2 * T_STEPS);

  // ---- stage y into LDS (coalesced float4) ----
  {
    const float4* g = (const float4*)yrow;
    float4* l = (float4*)y_lds;
#pragma unroll
    for (int i = 0; i < 16; ++i) l[i * 64 + lane] = g[i * 64 + lane];
  }
  __syncthreads();

  // ---- per-round-phase lane constants ----
  Ctx cx;
#pragma unroll
  for (int rp = 0; rp < 3; ++rp) {
    const int pA = 2 * rp, pB = 2 * rp + 1;
    const int mB = MARR[pB];
    float sa, sb; int pd;
    mk(pA, lane, sa, sb, pd);        cx.saeA[rp] = sa;  cx.sbeA[rp] = sb;  const int pdA = pd;
    mk(pA, lane ^ mB, sa, sb, pd);   cx.saeA2[rp] = sa; cx.sbeA2[rp] = sb; const int pdA2 = pd;
    mk(pB, lane, sa, sb, pd);        cx.saeB[rp] = sa;  cx.sbeB[rp] = sb;  const int pdB = pd;
    cx.pq0[rp] = (unsigned)(pdA  | (pdB << 1));
    cx.pq1[rp] = (unsigned)(pdA2 | (pdB << 1));
    cx.pdmA[rp]  = __ballot(pdA != 0);
    cx.pdmA2[rp] = __ballot(pdA2 != 0);
    cx.pdmB[rp]  = __ballot(pdB != 0);
  }
  // ---- probe permlane swap output-register convention -> uniform masks ----
  {
    const u64 ODD16 = 0xFFFF0000FFFF0000ull;   // lanes with (lane>>4)&1 == 1
    const u64 HI32  = 0xFFFFFFFF00000000ull;   // lanes >= 32
#if __has_builtin(__builtin_amdgcn_permlane16_swap)
    uint2v p16 = __builtin_amdgcn_permlane16_swap((unsigned)lane, (unsigned)lane, false, false);
    const bool rxo = ((unsigned)__builtin_amdgcn_readlane((int)p16.x, 0) == 16u);
    cx.mrx16 = rxo ? ~ODD16 : ODD16;
#else
    cx.mrx16 = 0;
#endif
#if __has_builtin(__builtin_amdgcn_permlane32_swap)
    uint2v p32 = __builtin_amdgcn_permlane32_swap((unsigned)lane, (unsigned)lane, false, false);
    const bool rxh = ((unsigned)__builtin_amdgcn_readlane((int)p32.x, 0) == 32u);
    cx.mrx32 = rxh ? ~HI32 : HI32;
#else
    cx.mrx32 = 0;
#endif
  }

  // ---- forward ACS: LDS->reg double-buffered prefetch, hoisted bm blocks ----
  float cum = (lane == 0) ? 0.0f : LARGEF;
  unsigned word = (unsigned)lane;
  float bmA[12], bmA2[12], bmB[12];
  float4 cur[12], nxt[12];
  const float4* y4 = (const float4*)y_lds;
#pragma unroll
  for (int j = 0; j < 12; ++j) cur[j] = y4[j];               // chunk 0
  for (int cc = 0; cc < 42; ++cc) {
    const int c0 = 2 * cc;
    bmcalc3<12>(cur, bmA, bmA2, bmB, cx);
#pragma unroll
    for (int j = 0; j < 12; ++j) nxt[j] = y4[12 * (c0 + 1) + j];   // prefetch c0+1
    frounds<12, 0>(cum, word, bmA, bmA2, bmB, cx);
    tbf[c0 * 64 + lane] = word; word = (unsigned)lane;
    bmcalc3<12>(nxt, bmA, bmA2, bmB, cx);
#pragma unroll
    for (int j = 0; j < 12; ++j) cur[j] = y4[12 * (c0 + 2) + j];   // prefetch c0+2
    frounds<12, 0>(cum, word, bmA, bmA2, bmB, cx);
    tbf[(c0 + 1) * 64 + lane] = word; word = (unsigned)lane;
  }
  // cur = chunk 84; tail (steps 2040..2047) = float4 idx 1020..1023
  bmcalc3<12>(cur, bmA, bmA2, bmB, cx);
#pragma unroll
  for (int j = 0; j < 4; ++j) nxt[j] = y4[1020 + j];
  frounds<12, 0>(cum, word, bmA, bmA2, bmB, cx);
  tbf[84 * 64 + lane] = word; word = (unsigned)lane;
  bmcalc3<4>(nxt, bmA, bmA2, bmB, cx);
  frounds<4, 0>(cum, word, bmA, bmA2, bmB, cx);
  tbf[85 * 64 + lane] = word;

  // ---- terminal argmin over true states (tie -> smallest state) ----
  // final labeling = phase 2048%6 = 2: state bit j from C[(2+j)%6] = {12,8,16,32,5,6}
  const int stf = par6(lane & 12) | (par6(lane & 8) << 1) | (par6(lane & 16) << 2) |
                  (par6(lane & 32) << 3) | (par6(lane & 5) << 4) | (par6(lane & 6) << 5);
  float v = cum; int bs = stf; int bl = lane;
#pragma unroll
  for (int off = 32; off >= 1; off >>= 1) {
    const float ov = __shfl_xor(v, off, 64);
    const int os = __shfl_xor(bs, off, 64);
    const int ol = __shfl_xor(bl, off, 64);
    if (ov < v || (ov == v && os < bs)) { v = ov; bs = os; bl = ol; }
  }
  int lam = __builtin_amdgcn_readfirstlane(bl);

  // ---- reconstruction: 86 chunk hops, prefetched rows, bits stored per hop ----
  const size_t ob = (size_t)b * T_STEPS;
  unsigned row = tbf[85 * 64 + lane];
  for (int c = 85; c >= 0; --c) {
    unsigned nrow = 0;
    if (c > 0) nrow = tbf[(c - 1) * 64 + lane];          // prefetch (addr indep of lam)
    const unsigned w = (unsigned)__builtin_amdgcn_readlane((int)row, lam);
    const int nb = (c == 85) ? 8 : 24;
    if (lane < nb) out[ob + c * 24 + lane] = (float)((w >> (6 + lane)) & 1u);
    lam = (int)(w & 63u);
    row = nrow;
  }
}

extern "C" void kernel_launch(void* const* d_in, const int* in_sizes, int n_in,
                              void* d_out, int out_size, void* d_ws, size_t ws_size,
                              hipStream_t stream) {
  const float* in = (const float*)d_in[0];
  float* out = (float*)d_out;
  (void)in_sizes; (void)n_in; (void)out_size; (void)d_ws; (void)ws_size;
  viterbi_kernel<<<dim3(512), dim3(64), 0, stream>>>(in, out);
}

// Round 9
// 72.405 us; speedup vs baseline: 1.4520x; 1.4520x over previous
//
#include <hip/hip_runtime.h>
#include <stdint.h>

#define T_STEPS 2048
#define NCHUNK  86            // 85 full 24-step chunks + one 8-step tail chunk
#define LARGEF  1.0e9f
typedef unsigned long long u64;
typedef unsigned uint2v __attribute__((ext_vector_type(2)));

__device__ __forceinline__ int par6(int x) { return __builtin_popcount((unsigned)x) & 1; }

// dual-basis functionals C; exchange masks m={1,2,7,15,16,32} (verified r2-r8)
constexpr int CARR[6] = {5, 6, 12, 8, 16, 32};

template<int CTRL>
__device__ __forceinline__ float xdpp(float x) {
  return __int_as_float(__builtin_amdgcn_update_dpp(0, __float_as_int(x), CTRL, 0xF, 0xF, true));
}
template<int CTRL>
__device__ __forceinline__ unsigned xdpp_u(unsigned x) {
  return (unsigned)__builtin_amdgcn_update_dpp(0, (int)x, CTRL, 0xF, 0xF, true);
}

// select by uniform 64-bit wave mask (SGPR pair): bit=1 -> take b_true
__device__ __forceinline__ unsigned selmask_u(unsigned a_false, unsigned b_true, u64 m) {
  unsigned out;
  asm("v_cndmask_b32 %0, %1, %2, %3" : "=v"(out) : "v"(a_false), "v"(b_true), "s"(m));
  return out;
}

__device__ __forceinline__ unsigned exch16_u(unsigned x, u64 mrx) {
#if __has_builtin(__builtin_amdgcn_permlane16_swap)
  uint2v r = __builtin_amdgcn_permlane16_swap(x, x, false, false);
  return selmask_u(r.y, r.x, mrx);
#else
  (void)mrx;
  return (unsigned)__builtin_amdgcn_ds_swizzle((int)x, 0x401F);
#endif
}
__device__ __forceinline__ unsigned exch32_u(unsigned x, u64 mrx) {
#if __has_builtin(__builtin_amdgcn_permlane32_swap)
  uint2v r = __builtin_amdgcn_permlane32_swap(x, x, false, false);
  return selmask_u(r.y, r.x, mrx);
#else
  (void)mrx;
  return (unsigned)__shfl_xor((int)x, 32, 64);
#endif
}
__device__ __forceinline__ float exch16_f(float x, u64 mrx) {
  return __uint_as_float(exch16_u(__float_as_uint(x), mrx));
}
__device__ __forceinline__ float exch32_f(float x, u64 mrx) {
  return __uint_as_float(exch32_u(__float_as_uint(x), mrx));
}

struct Ctx {
  float sae[6], sbe[6];
  unsigned pdu[6];   // decoded-bit constant per phase (0/1)
  unsigned sgn[6];   // sign-flip for decision: pd ? 0 : 0x80000000
  u64 pdm[6];        // uniform mask: lanes with odd own-pred parity
  u64 mrx16, mrx32;  // permlane swap r.x-select masks
};

// ---- hoisted branch metrics for a chunk (independent ILP block) ----
template<int N>
__device__ __forceinline__ void bmcalc(const float4 (&fy)[12], float (&bm)[24], const Ctx& cx) {
#pragma unroll
  for (int k = 0; k < N; ++k) {
    const int ph = k % 6;
    const float y0 = (k & 1) ? fy[k >> 1].z : fy[k >> 1].x;
    const float y1 = (k & 1) ? fy[k >> 1].w : fy[k >> 1].y;
    bm[k] = fmaf(cx.sae[ph], y0, cx.sbe[ph] * y1);   // bit-exact vs ref
  }
}

// ---- N ACS steps, start phase 0; word = [path bits 6..][anc 0..5] ----
// decision d = chosen-pred LSB, all-VALU sign-xor trick (no ballots/SALU):
//   d = ((cA-cB) ^ (pd?0:signbit)) < 0 ; exact-tie -> +/-0 -> d=0 (argmin-first)
template<int N, int K>
__device__ __forceinline__ void fsteps(float& cum, unsigned& word,
                                       const float (&bm)[24], const Ctx& cx) {
  if constexpr (K < N) {
    constexpr int ph = K % 6;
    float ex; unsigned exw;
    if constexpr (ph == 0)      { ex = xdpp<0xB1>(cum);  exw = xdpp_u<0xB1>(word); }   // xor 1
    else if constexpr (ph == 1) { ex = xdpp<0x4E>(cum);  exw = xdpp_u<0x4E>(word); }   // xor 2
    else if constexpr (ph == 2) { ex = xdpp<0x141>(cum); exw = xdpp_u<0x141>(word); }  // xor 7
    else if constexpr (ph == 3) { ex = xdpp<0x140>(cum); exw = xdpp_u<0x140>(word); }  // xor 15
    else if constexpr (ph == 4) { ex = exch16_f(cum, cx.mrx16); exw = exch16_u(word, cx.mrx16); } // xor 16
    else                        { ex = exch32_f(cum, cx.mrx32); exw = exch32_u(word, cx.mrx32); } // xor 32
    const float cA = cum + bm[K];   // own-pred candidate
    const float cB = ex - bm[K];    // partner-pred candidate
    const float D  = cA - cB;       // sign exact; zero iff true tie
    cum = fminf(cA, cB);
    const unsigned w0 = selmask_u(word, exw, cx.pdm[ph]);  // pred-LSB-0 ancestor word
    const unsigned w1 = selmask_u(exw, word, cx.pdm[ph]);  // pred-LSB-1 ancestor word
    const bool d = __uint_as_float(__float_as_uint(D) ^ cx.sgn[ph]) < 0.0f;
    word = (d ? w1 : w0) | (cx.pdu[ph] << (6 + K));
    fsteps<N, K + 1>(cum, word, bm, cx);
  }
}

__global__ __launch_bounds__(64, 1) void viterbi_kernel(const float* __restrict__ in,
                                                        float* __restrict__ out) {
  __shared__ float y_lds[2 * T_STEPS];     // 16 KB staged input row
  __shared__ unsigned tbf[NCHUNK * 64];    // 21.5 KB flushed path/anc words

  const int b = blockIdx.x;
  const int lane = threadIdx.x;
  const float* yrow = in + (size_t)b * (2 * T_STEPS);

  // ---- stage y into LDS (coalesced float4) ----
  {
    const float4* g = (const float4*)yrow;
    float4* l = (float4*)y_lds;
#pragma unroll
    for (int i = 0; i < 16; ++i) l[i * 64 + lane] = g[i * 64 + lane];
  }
  __syncthreads();

  // ---- per-phase lane constants ----
  Ctx cx;
#pragma unroll
  for (int ph = 0; ph < 6; ++ph) {
    const int pdv = par6(lane & CARR[ph]);
    int t = 0;
#pragma unroll
    for (int j = 0; j < 5; ++j) t |= par6(lane & CARR[(ph + 1 + j) % 6]) << j;
    t |= pdv << 5;
    const float sa = 1.0f - 2.0f * (float)par6(t & 45);   // poly 1011011
    const float sb = 1.0f - 2.0f * (float)par6(t & 60);   // poly 1111001
    cx.sae[ph] = pdv ? -sa : sa;
    cx.sbe[ph] = pdv ? -sb : sb;
    cx.pdu[ph] = (unsigned)pdv;
    cx.sgn[ph] = pdv ? 0u : 0x80000000u;
    cx.pdm[ph] = __ballot(pdv != 0);
  }
  // ---- probe permlane swap output-register convention -> uniform masks ----
  {
    const u64 ODD16 = 0xFFFF0000FFFF0000ull;   // lanes with (lane>>4)&1 == 1
    const u64 HI32  = 0xFFFFFFFF00000000ull;   // lanes >= 32
#if __has_builtin(__builtin_amdgcn_permlane16_swap)
    uint2v p16 = __builtin_amdgcn_permlane16_swap((unsigned)lane, (unsigned)lane, false, false);
    const bool rxo = ((unsigned)__builtin_amdgcn_readlane((int)p16.x, 0) == 16u);
    cx.mrx16 = rxo ? ~ODD16 : ODD16;
#else
    cx.mrx16 = 0;
#endif
#if __has_builtin(__builtin_amdgcn_permlane32_swap)
    uint2v p32 = __builtin_amdgcn_permlane32_swap((unsigned)lane, (unsigned)lane, false, false);
    const bool rxh = ((unsigned)__builtin_amdgcn_readlane((int)p32.x, 0) == 32u);
    cx.mrx32 = rxh ? ~HI32 : HI32;
#else
    cx.mrx32 = 0;
#endif
  }

  // ---- forward ACS: LDS->reg double-buffered prefetch, hoisted bm blocks ----
  float cum = (lane == 0) ? 0.0f : LARGEF;
  unsigned word = (unsigned)lane;
  float bm[24];
  float4 cur[12], nxt[12];
  const float4* y4 = (const float4*)y_lds;
#pragma unroll
  for (int j = 0; j < 12; ++j) cur[j] = y4[j];               // chunk 0
  for (int cc = 0; cc < 42; ++cc) {
    const int c0 = 2 * cc;
    bmcalc<24>(cur, bm, cx);
#pragma unroll
    for (int j = 0; j < 12; ++j) nxt[j] = y4[12 * (c0 + 1) + j];   // prefetch c0+1
    fsteps<24, 0>(cum, word, bm, cx);
    tbf[c0 * 64 + lane] = word; word = (unsigned)lane;
    bmcalc<24>(nxt, bm, cx);
#pragma unroll
    for (int j = 0; j < 12; ++j) cur[j] = y4[12 * (c0 + 2) + j];   // prefetch c0+2
    fsteps<24, 0>(cum, word, bm, cx);
    tbf[(c0 + 1) * 64 + lane] = word; word = (unsigned)lane;
  }
  // cur = chunk 84; tail (steps 2040..2047) = float4 idx 1020..1023
  bmcalc<24>(cur, bm, cx);
#pragma unroll
  for (int j = 0; j < 4; ++j) nxt[j] = y4[1020 + j];
  fsteps<24, 0>(cum, word, bm, cx);
  tbf[84 * 64 + lane] = word; word = (unsigned)lane;
  bmcalc<8>(nxt, bm, cx);
  fsteps<8, 0>(cum, word, bm, cx);
  tbf[85 * 64 + lane] = word;

  // ---- terminal argmin over true states (tie -> smallest state) ----
  // final labeling = phase 2048%6 = 2: state bit j from C[(2+j)%6] = {12,8,16,32,5,6}
  const int stf = par6(lane & 12) | (par6(lane & 8) << 1) | (par6(lane & 16) << 2) |
                  (par6(lane & 32) << 3) | (par6(lane & 5) << 4) | (par6(lane & 6) << 5);
  float v = cum; int bs = stf; int bl = lane;
#pragma unroll
  for (int off = 32; off >= 1; off >>= 1) {
    const float ov = __shfl_xor(v, off, 64);
    const int os = __shfl_xor(bs, off, 64);
    const int ol = __shfl_xor(bl, off, 64);
    if (ov < v || (ov == v && os < bs)) { v = ov; bs = os; bl = ol; }
  }
  int lam = __builtin_amdgcn_readfirstlane(bl);

  // ---- reconstruction: 86 chunk hops, prefetched rows, bits stored per hop ----
  const size_t ob = (size_t)b * T_STEPS;
  unsigned row = tbf[85 * 64 + lane];
  for (int c = 85; c >= 0; --c) {
    unsigned nrow = 0;
    if (c > 0) nrow = tbf[(c - 1) * 64 + lane];          // prefetch (addr indep of lam)
    const unsigned w = (unsigned)__builtin_amdgcn_readlane((int)row, lam);
    const int nb = (c == 85) ? 8 : 24;
    if (lane < nb) out[ob + c * 24 + lane] = (float)((w >> (6 + lane)) & 1u);
    lam = (int)(w & 63u);
    row = nrow;
  }
}

extern "C" void kernel_launch(void* const* d_in, const int* in_sizes, int n_in,
                              void* d_out, int out_size, void* d_ws, size_t ws_size,
                              hipStream_t stream) {
  const float* in = (const float*)d_in[0];
  float* out = (float*)d_out;
  (void)in_sizes; (void)n_in; (void)out_size; (void)d_ws; (void)ws_size;
  viterbi_kernel<<<dim3(512), dim3(64), 0, stream>>>(in, out);
}